// Round 7
// baseline (1130.275 us; speedup 1.0000x reference)
//
#include <hip/hip_runtime.h>
#include <hip/hip_bf16.h>
#include <math.h>

typedef unsigned short u16;
using bf16x8 = __attribute__((ext_vector_type(8))) short;
using f32x4  = __attribute__((ext_vector_type(4))) float;

__device__ inline float b2f(u16 u) {
  unsigned v = ((unsigned)u) << 16;
  return __builtin_bit_cast(float, v);
}
__device__ inline u16 f2b(float f) {
  unsigned u = __builtin_bit_cast(unsigned, f);
  u += 0x7fffu + ((u >> 16) & 1u);
  return (u16)(u >> 16);
}
__device__ inline float gelu_f(float x) {
  float x3 = x * x * x;
  return 0.5f * x * (1.f + tanhf(0.7978845608028654f * (x + 0.044715f * x3)));
}
__device__ inline void gload_lds16(const void* g, void* lds) {
  __builtin_amdgcn_global_load_lds((const __attribute__((address_space(1))) void*)g,
                                   (__attribute__((address_space(3))) void*)lds,
                                   16, 0, 0);
}

// ---------------------------------------------------------------------------
// Persistent recurrence kernel: 256 blocks x 256 threads, block owns 16 rows.
// H lives in LDS (16 rows x 512 bf16, 16B-chunk XOR-swizzled by row&7).
// Caches K'/VW in global (block-private rows). Weights streamed L2->regs.
// ---------------------------------------------------------------------------

// GEMM phase: [16 x COLS] = Hs[16x512] @ B (BT given, [COLS][512] bf16).
// COLS=1024: cols 0..511 -> Kc slot (+bias), 512..1023 -> VWc slot.
// F32OUT: COLS=512, write f32 to outp.
template<int COLS, int F32OUT>
__device__ __forceinline__ void gemm_phase(
    const u16* Hs, const u16* __restrict__ BT, const u16* __restrict__ bias,
    u16* __restrict__ Kc, u16* __restrict__ VWc, float* __restrict__ outp,
    int r0, int slot, int lane, int wid)
{
  // A fragments: 16 k-steps of 32; lane holds row=lane&15, k-chunk lane>>4
  bf16x8 areg[16];
  {
    const int r = lane & 15, hi = lane >> 4;
    #pragma unroll
    for (int kk = 0; kk < 16; ++kk) {
      const int c16 = (kk * 4 + hi) ^ (r & 7);
      areg[kk] = *(const bf16x8*)((const char*)Hs + r * 1024 + c16 * 16);
    }
  }
  constexpr int NCT = COLS / 64;          // col-tiles per wave
  const int colb = wid * (COLS / 4);
  const int rowb = (lane >> 4) * 4;
  const int hi = lane >> 4;

  auto loadB = [&](bf16x8* dst, int ct) {
    const u16* base = BT + (size_t)(colb + ct * 16 + (lane & 15)) * 512 + hi * 8;
    #pragma unroll
    for (int kk = 0; kk < 16; ++kk)
      dst[kk] = *(const bf16x8*)(base + kk * 32);
  };
  auto epi = [&](int ct, const f32x4& a) {
    #pragma unroll
    for (int i = 0; i < 4; ++i) {
      const int g = colb + ct * 16 + (lane & 15);
      const int row = r0 + rowb + i;
      const float v = a[i];
      if constexpr (F32OUT) {
        outp[(size_t)row * 512 + g] = v;
      } else {
        if (g < 512) {
          Kc[((size_t)row * 16 + slot) * 512 + g] = f2b(v + b2f(bias[g]));
        } else {
          VWc[((size_t)row * 16 + slot) * 512 + (g - 512)] = f2b(v);
        }
      }
    }
  };

  bf16x8 b0[16], b1[16];
  #pragma unroll
  for (int cp = 0; cp < NCT / 2; ++cp) {
    loadB(b0, 2 * cp);
    loadB(b1, 2 * cp + 1);
    f32x4 a0 = {0.f, 0.f, 0.f, 0.f}, a1 = {0.f, 0.f, 0.f, 0.f};
    #pragma unroll
    for (int kk = 0; kk < 16; ++kk) {
      a0 = __builtin_amdgcn_mfma_f32_16x16x32_bf16(areg[kk], b0[kk], a0, 0, 0, 0);
      a1 = __builtin_amdgcn_mfma_f32_16x16x32_bf16(areg[kk], b1[kk], a1, 0, 0, 0);
    }
    epi(2 * cp, a0);
    epi(2 * cp + 1, a1);
  }
}

__global__ __launch_bounds__(256, 1)
void persist_kernel(const u16* __restrict__ xb,
                    const u16* __restrict__ ITn, const u16* __restrict__ PT2,
                    const u16* __restrict__ W2T, const u16* __restrict__ biasC,
                    const float* __restrict__ temb,
                    u16* __restrict__ Kc, u16* __restrict__ VWc,
                    float* __restrict__ outp)
{
  __shared__ alignas(16) u16 Hs[16 * 512];   // byte: r*1024 + (c16^(r&7))*16
  const int tid = threadIdx.x, lane = tid & 63, wid = tid >> 6;
  const int r0 = blockIdx.x * 16;
  const float scale = 0.04419417382415922f;  // 1/sqrt(512)

  // stage x rows -> Hs (source pre-swizzled so LDS dest stays linear)
  #pragma unroll
  for (int p = 0; p < 4; ++p) {
    const int s16 = (p * 4 + wid) * 64 + lane;    // 16B-chunk slot 0..1023
    const int r = s16 >> 6, c16 = s16 & 63;
    gload_lds16(xb + (size_t)(r0 + r) * 512 + (size_t)(c16 ^ (r & 7)) * 8,
                (char*)Hs + (size_t)(p * 4 + wid) * 1024);
  }
  asm volatile("s_waitcnt vmcnt(0)" ::: "memory");
  __syncthreads();

  for (int t = -1; t < 15; ++t) {
    // [K'_{t+1} | VW_{t+1}] = Hs @ P  (init: P=ITn no bias via zero row)
    gemm_phase<1024, 0>(Hs, (t == -1) ? ITn : PT2,
                        biasC + (size_t)((t == -1) ? 15 : t) * 512,
                        Kc, VWc, nullptr, r0, t + 1, lane, wid);
    __syncthreads();

    // attend: query = own H row, slots 0..t+1 -> new H row (gelu + temb)
    const int n = t + 2;
    const float* tv = temb + (size_t)((t == 14) ? 16 : t + 1) * 512;
    for (int rr = 0; rr < 4; ++rr) {
      const int r = wid * 4 + rr;
      const bf16x8 q8 = *(const bf16x8*)((const char*)Hs + r * 1024 +
                                         ((lane ^ (r & 7)) << 4));
      float qf[8];
      #pragma unroll
      for (int j = 0; j < 8; ++j) qf[j] = b2f((u16)q8[j]);
      const u16* kbase = Kc + ((size_t)(r0 + r) * 16) * 512 + lane * 8;
      const u16* vbase = VWc + ((size_t)(r0 + r) * 16) * 512 + lane * 8;
      float s[16];
      float mx = -1e30f;
      #pragma unroll
      for (int j = 0; j < 16; ++j) {
        if (j < n) {
          const bf16x8 k8 = *(const bf16x8*)(kbase + j * 512);
          float d = 0.f;
          #pragma unroll
          for (int e = 0; e < 8; ++e) d += qf[e] * b2f((u16)k8[e]);
          #pragma unroll
          for (int off = 32; off > 0; off >>= 1) d += __shfl_xor(d, off, 64);
          s[j] = d * scale;
          mx = fmaxf(mx, s[j]);
        }
      }
      float p[16], sum = 0.f;
      #pragma unroll
      for (int j = 0; j < 16; ++j)
        if (j < n) { p[j] = expf(s[j] - mx); sum += p[j]; }
      const float inv = 1.f / sum;
      float a[8] = {};
      #pragma unroll
      for (int j = 0; j < 16; ++j) {
        if (j < n) {
          const bf16x8 v8 = *(const bf16x8*)(vbase + j * 512);
          const float pj = p[j] * inv;
          #pragma unroll
          for (int e = 0; e < 8; ++e) a[e] += pj * b2f((u16)v8[e]);
        }
      }
      bf16x8 o;
      #pragma unroll
      for (int e = 0; e < 8; ++e)
        o[e] = (short)f2b(gelu_f(a[e] + tv[lane * 8 + e]));
      *(bf16x8*)((char*)Hs + r * 1024 + ((lane ^ (r & 7)) << 4)) = o;
    }
    __syncthreads();
  }

  // final: out = H @ W2 (f32)
  gemm_phase<512, 1>(Hs, W2T, nullptr, nullptr, nullptr, outp, r0, 0, lane, wid);
}

// ---------------------------------------------------------------------------
// Weight-precompute batched GEMMs (unchanged structure from prior rounds)
// ---------------------------------------------------------------------------
struct BatchJobs {
  const u16* A[5];
  const u16* BT[5];
  u16* O[5];
  int M[5];
};

__global__ __launch_bounds__(256)
void gemm_batch(BatchJobs jb)
{
  constexpr int BM = 128, BN = 64, WN = 32, NR = 2, MR = 4;
  const int z = blockIdx.z;
  if ((int)blockIdx.x * BM >= jb.M[z]) return;
  const u16* __restrict__ Aptr = jb.A[z];
  const u16* __restrict__ BT   = jb.BT[z];
  u16* __restrict__ Optr       = jb.O[z];

  __shared__ alignas(16) char Ash[3][BM * 128];
  __shared__ alignas(16) char Bsh[3][BN * 128];
  const int tid = threadIdx.x, lane = tid & 63, wid = tid >> 6;
  const int wm = wid >> 1, wn = wid & 1;
  const int bm = blockIdx.x, bn = blockIdx.y;

  const int rIn = lane >> 3;
  const int c16log = (lane & 7) ^ (rIn & 7);

  auto stage = [&](int buf, int kt) {
    #pragma unroll
    for (int i = 0; i < 4; ++i) {
      int c = wid * 4 + i;
      int row = c * 8 + rIn;
      gload_lds16(Aptr + (size_t)(bm * BM + row) * 512 + kt + c16log * 8,
                  Ash[buf] + c * 1024);
    }
    #pragma unroll
    for (int i = 0; i < 2; ++i) {
      int c = wid * 2 + i;
      int row = c * 8 + rIn;
      gload_lds16(BT + (size_t)(bn * BN + row) * 512 + kt + c16log * 8,
                  Bsh[buf] + c * 1024);
    }
  };

  f32x4 acc[MR][NR] = {};
  stage(0, 0);
  stage(1, 64);
  #pragma unroll
  for (int kt = 0; kt < 8; ++kt) {
    const int cb = kt % 3;
    if (kt < 6) {
      stage((kt + 2) % 3, (kt + 2) * 64);
      asm volatile("s_waitcnt vmcnt(12)" ::: "memory");
    } else if (kt == 6) {
      asm volatile("s_waitcnt vmcnt(6)" ::: "memory");
    } else {
      asm volatile("s_waitcnt vmcnt(0)" ::: "memory");
    }
    __builtin_amdgcn_s_barrier();
    asm volatile("" ::: "memory");
    #pragma unroll
    for (int kk = 0; kk < 64; kk += 32) {
      bf16x8 af[MR], bfr[NR];
      #pragma unroll
      for (int m = 0; m < MR; ++m) {
        int R = wm * 64 + m * 16 + (lane & 15);
        int c16 = (kk >> 3) + (lane >> 4);
        af[m] = *(const bf16x8*)(Ash[cb] + R * 128 + ((c16 ^ (R & 7)) << 4));
      }
      #pragma unroll
      for (int n = 0; n < NR; ++n) {
        int R = wn * WN + n * 16 + (lane & 15);
        int c16 = (kk >> 3) + (lane >> 4);
        bfr[n] = *(const bf16x8*)(Bsh[cb] + R * 128 + ((c16 ^ (R & 7)) << 4));
      }
      #pragma unroll
      for (int m = 0; m < MR; ++m)
        #pragma unroll
        for (int n = 0; n < NR; ++n)
          acc[m][n] = __builtin_amdgcn_mfma_f32_16x16x32_bf16(af[m], bfr[n], acc[m][n], 0, 0, 0);
    }
    asm volatile("" ::: "memory");
    __builtin_amdgcn_s_barrier();
    asm volatile("" ::: "memory");
  }

  const int row0 = bm * BM + wm * 64;
  const int col0 = bn * BN + wn * WN;
  #pragma unroll
  for (int m = 0; m < MR; ++m)
    #pragma unroll
    for (int n = 0; n < NR; ++n)
      #pragma unroll
      for (int i = 0; i < 4; ++i) {
        int row = row0 + m * 16 + (lane >> 4) * 4 + i;
        int col = col0 + n * 16 + (lane & 15);
        Optr[(size_t)row * 512 + col] = f2b(acc[m][n][i]);
      }
}

// One merged prep launch: 5 transposes, 3 conversions, Wik zero-pad, biasK.
__global__ __launch_bounds__(256)
void prep_kernel(const float* __restrict__ x,   const float* __restrict__ Wik,
                 const float* __restrict__ Wiv, const float* __restrict__ Wq,
                 const float* __restrict__ Wk,  const float* __restrict__ Wv,
                 const float* __restrict__ W1,  const float* __restrict__ W2,
                 u16* __restrict__ W1T, u16* __restrict__ W2T, u16* __restrict__ WqT,
                 u16* __restrict__ WkT, u16* __restrict__ WvT,
                 u16* __restrict__ W2b, u16* __restrict__ Wivb, u16* __restrict__ xb,
                 u16* __restrict__ Wikpadb, u16* __restrict__ biasKpad)
{
  const int bid = blockIdx.x, tid = threadIdx.x;
  if (bid < 1280) {                       // transpose-convert f32[512][512]->bf16 T
    __shared__ float tile[32][33];
    const int mat = bid >> 8, local = bid & 255;
    const float* in = (mat == 0) ? W1 : (mat == 1) ? W2 : (mat == 2) ? Wq
                    : (mat == 3) ? Wk : Wv;
    u16* out = (mat == 0) ? W1T : (mat == 1) ? W2T : (mat == 2) ? WqT
             : (mat == 3) ? WkT : WvT;
    const int tx = tid & 31, ty = tid >> 5;
    const int c0 = (local & 15) * 32, r0 = (local >> 4) * 32;
    #pragma unroll
    for (int rr = 0; rr < 32; rr += 8)
      tile[ty + rr][tx] = in[(size_t)(r0 + ty + rr) * 512 + c0 + tx];
    __syncthreads();
    #pragma unroll
    for (int rr = 0; rr < 32; rr += 8)
      out[(size_t)(c0 + ty + rr) * 512 + r0 + tx] = f2b(tile[tx][ty + rr]);
  } else if (bid < 3840) {                // f32->bf16 row-major conversions
    const float* in; u16* out; int local;
    if (bid < 1536)      { in = W2;  out = W2b;  local = bid - 1280; }
    else if (bid < 1792) { in = Wiv; out = Wivb; local = bid - 1536; }
    else                 { in = x;   out = xb;   local = bid - 1792; }
    const int i = local * 256 + tid;
    const float4 v = ((const float4*)in)[i];
    ushort4 o;
    o.x = f2b(v.x); o.y = f2b(v.y); o.z = f2b(v.z); o.w = f2b(v.w);
    ((ushort4*)out)[i] = o;
  } else if (bid < 4096) {                // Wik [512][448] -> bf16 [512][512] pad
    const int local = bid - 3840;
    const int e = local * 1024 + tid * 4;
    const int r = e >> 9, c0 = e & 511;
    ushort4 o;
    float v0 = (c0 + 0 < 448) ? Wik[(size_t)r * 448 + c0 + 0] : 0.f;
    float v1 = (c0 + 1 < 448) ? Wik[(size_t)r * 448 + c0 + 1] : 0.f;
    float v2 = (c0 + 2 < 448) ? Wik[(size_t)r * 448 + c0 + 2] : 0.f;
    float v3 = (c0 + 3 < 448) ? Wik[(size_t)r * 448 + c0 + 3] : 0.f;
    o.x = f2b(v0); o.y = f2b(v1); o.z = f2b(v2); o.w = f2b(v3);
    *(ushort4*)(Wikpadb + (size_t)r * 512 + c0) = o;
  } else {                                // biasK padded to 128 rows, bf16
    const int local = bid - 4096;
    const int t = local >> 1;
    const int col = ((local & 1) << 8) + tid;
    float acc = 0.f;
    if (t < 15) {
      #pragma unroll
      for (int r = 0; r < 64; ++r) {
        float tenc = 3.14159265358979323846f * exp2f(-(float)r);
        acc += sinf((float)t * tenc) * Wk[(size_t)(512 + r) * 512 + col];
      }
    }
    biasKpad[(size_t)t * 512 + col] = f2b(acc);
  }
}

extern "C" void kernel_launch(void* const* d_in, const int* in_sizes, int n_in,
                              void* d_out, int out_size, void* d_ws, size_t ws_size,
                              hipStream_t stream)
{
  const float* x    = (const float*)d_in[0];
  const float* Wik  = (const float*)d_in[1];
  const float* Wiv  = (const float*)d_in[2];
  const float* Wq   = (const float*)d_in[3];
  const float* Wk   = (const float*)d_in[4];
  const float* Wv   = (const float*)d_in[5];
  const float* W1   = (const float*)d_in[6];
  const float* W2   = (const float*)d_in[7];
  const float* temb = (const float*)d_in[8];

  char* ws = (char*)d_ws;
  size_t off = 0;
  auto alloc = [&](size_t bytes) {
    char* p = ws + off;
    off += (bytes + 255) & ~(size_t)255;
    return p;
  };
  const size_t SQ = (size_t)512 * 512 * 2;
  u16* W1T     = (u16*)alloc(SQ);
  u16* W2T     = (u16*)alloc(SQ);
  u16* WqT     = (u16*)alloc(SQ);
  u16* WkT     = (u16*)alloc(SQ);
  u16* WvT     = (u16*)alloc(SQ);
  u16* W2b     = (u16*)alloc(SQ);
  u16* Wivb    = (u16*)alloc(SQ);
  u16* Wikpadb = (u16*)alloc(SQ);
  u16* biasKpad= (u16*)alloc((size_t)128 * 512 * 2);
  u16* W2Wq    = (u16*)alloc(SQ);
  u16* W2WkD   = (u16*)alloc(SQ);
  u16* W2Wv    = (u16*)alloc(SQ);
  u16* biasC   = (u16*)alloc((size_t)128 * 512 * 2);
  u16* PT2     = (u16*)alloc((size_t)1024 * 512 * 2);  // [M ; (W2WvW1)^T]
  u16* ITn     = (u16*)alloc((size_t)1024 * 512 * 2);  // [WzT ; (WivW1)^T]
  u16* xb      = (u16*)alloc((size_t)4096 * 512 * 2);
  u16* Kc      = (u16*)alloc((size_t)4096 * 16 * 512 * 2);  // K' cache
  u16* VWc     = (u16*)alloc((size_t)4096 * 16 * 512 * 2);  // V@W1 cache

  dim3 blk(256);
  prep_kernel<<<dim3(4352), blk, 0, stream>>>(
      x, Wik, Wiv, Wq, Wk, Wv, W1, W2,
      W1T, W2T, WqT, WkT, WvT, W2b, Wivb, xb, Wikpadb, biasKpad);

  // batch1: W2Wq = W2@Wq, W2WkD = W2@WkD, W2Wv = W2@Wv
  BatchJobs b1 = {};
  b1.A[0] = W2b; b1.BT[0] = WqT; b1.O[0] = W2Wq;  b1.M[0] = 512;
  b1.A[1] = W2b; b1.BT[1] = WkT; b1.O[1] = W2WkD; b1.M[1] = 512;
  b1.A[2] = W2b; b1.BT[2] = WvT; b1.O[2] = W2Wv;  b1.M[2] = 512;
  gemm_batch<<<dim3(4, 8, 3), blk, 0, stream>>>(b1);

  // batch2: M = W2Wq@(W2WkD)^T        -> PT2 rows 0..511
  //         (W2WvW1)^T = W1T@(W2Wv)^T -> PT2 rows 512..1023
  //         WzT = W2Wq@Wikpad^T       -> ITn rows 0..511
  //         (WivW1)^T = W1T@Wiv^T     -> ITn rows 512..1023
  //         biasC = biasKpad@(W2Wq)^T (rows 15..127 zero)
  BatchJobs b2 = {};
  b2.A[0] = W2Wq;     b2.BT[0] = W2WkD;   b2.O[0] = PT2;                       b2.M[0] = 512;
  b2.A[1] = W1T;      b2.BT[1] = W2Wv;    b2.O[1] = PT2 + (size_t)512 * 512;   b2.M[1] = 512;
  b2.A[2] = W2Wq;     b2.BT[2] = Wikpadb; b2.O[2] = ITn;                       b2.M[2] = 512;
  b2.A[3] = W1T;      b2.BT[3] = Wivb;    b2.O[3] = ITn + (size_t)512 * 512;   b2.M[3] = 512;
  b2.A[4] = biasKpad; b2.BT[4] = W2Wq;    b2.O[4] = biasC;                     b2.M[4] = 128;
  gemm_batch<<<dim3(4, 8, 5), blk, 0, stream>>>(b2);

  // persistent fused recurrence: init + 15 iterations + final, all in one.
  persist_kernel<<<dim3(256), blk, 0, stream>>>(
      xb, ITn, PT2, W2T, biasC, temb, Kc, VWc, (float*)d_out);
}